// Round 6
// baseline (160.047 us; speedup 1.0000x reference)
//
#include <hip/hip_runtime.h>

#define T_ 2048
#define B_ 2
#define H_ 12
#define C_ 768
#define M_ 4096  // B*T
#define BH_ (B_ * H_)
#define RSTR 2200  // reversed-e padded stride

typedef __attribute__((ext_vector_type(4))) float f32x4;
typedef __attribute__((ext_vector_type(16))) float f32x16;
typedef __attribute__((ext_vector_type(8))) __bf16 bf16x8;
typedef __attribute__((ext_vector_type(4))) __bf16 bf16x4;

// Packed fragment-major layouts (coalesced MFMA frag loads: addr = base + lane*8 elems):
//  Qp/Kp: [bh][tile=t>>5][kc=d>>4][lane=((d>>3)&1)*32 + (t&31)][j=d&7]   (tile stride 2048)
//  Vp:    [bh][chunk=t>>6][dhalf=d>>5][kc=(t&63)>>4][lane=(((t&63)>>3)&1)*32 + (d&31)][j=t&7]

// ---------------------------------------------------------------------------
// Stage-1 GEMM: qkv = x @ c_attn^T -> packed bf16 Qp, Kp, Vp
// ---------------------------------------------------------------------------
__global__ __launch_bounds__(256) void gemm_qkv(const float* __restrict__ A,
                                                const float* __restrict__ Bm,
                                                __bf16* __restrict__ Qp,
                                                __bf16* __restrict__ Kp,
                                                __bf16* __restrict__ Vp) {
  __shared__ __align__(16) __bf16 sA[128][40];
  __shared__ __align__(16) __bf16 sB[128][40];
  const int tid = threadIdx.x;
  const int m0 = blockIdx.y * 128, n0 = blockIdx.x * 128;
  const int lane = tid & 63, w = tid >> 6;
  const int wr = w >> 1, wc = w & 1;
  const int fr = lane & 15;
  const int ko = (lane >> 4) << 3;
  const int K = C_;
  f32x4 acc[4][4] = {};
  for (int k0 = 0; k0 < K; k0 += 32) {
#pragma unroll
    for (int i = 0; i < 4; ++i) {
      int f = tid + (i << 8);
      int row = f >> 3, c4 = (f & 7) << 2;
      f32x4 av = *(const f32x4*)(A + (size_t)(m0 + row) * K + k0 + c4);
      f32x4 bv = *(const f32x4*)(Bm + (size_t)(n0 + row) * K + k0 + c4);
      bf16x4 ah, bh;
#pragma unroll
      for (int j = 0; j < 4; ++j) { ah[j] = (__bf16)av[j]; bh[j] = (__bf16)bv[j]; }
      *(bf16x4*)&sA[row][c4] = ah;
      *(bf16x4*)&sB[row][c4] = bh;
    }
    __syncthreads();
    bf16x8 a[4], b[4];
#pragma unroll
    for (int m = 0; m < 4; ++m) a[m] = *(const bf16x8*)&sA[wr * 64 + m * 16 + fr][ko];
#pragma unroll
    for (int n = 0; n < 4; ++n) b[n] = *(const bf16x8*)&sB[wc * 64 + n * 16 + fr][ko];
#pragma unroll
    for (int m = 0; m < 4; ++m)
#pragma unroll
      for (int n = 0; n < 4; ++n)
        acc[m][n] = __builtin_amdgcn_mfma_f32_16x16x32_bf16(a[m], b[n], acc[m][n], 0, 0, 0);
    __syncthreads();
  }
  const int orow = (lane >> 4) << 2, ocol = lane & 15;
#pragma unroll
  for (int m = 0; m < 4; ++m)
#pragma unroll
    for (int n = 0; n < 4; ++n) {
      int r = m0 + wr * 64 + m * 16 + orow;  // token (4 consecutive via j)
      int c = n0 + wc * 64 + n * 16 + ocol;  // feature
      int sec = c / 768;
      int hd = c - sec * 768;
      int h = hd >> 6, d = hd & 63;
      int b = r >> 11, t = r & 2047;
      int bh = b * H_ + h;
      if (sec < 2) {
        int tile = t >> 5, rr = t & 31;
        int kc = d >> 4, half = (d >> 3) & 1, dj = d & 7;
        __bf16* dst = (sec == 0 ? Qp : Kp) + ((size_t)bh * 64 + tile) * 2048 +
                      kc * 512 + (half * 32 + rr) * 8 + dj;
#pragma unroll
        for (int j = 0; j < 4; ++j) dst[j * 8] = (__bf16)acc[m][n][j];  // rr+j
      } else {
        int chunk = t >> 6, sk = t & 63;
        int kc = sk >> 4, hf = (sk >> 3) & 1, j0 = sk & 7;  // j0 in {0,4}
        bf16x4 pk;
#pragma unroll
        for (int j = 0; j < 4; ++j) pk[j] = (__bf16)acc[m][n][j];
        *(bf16x4*)(Vp + ((size_t)bh * 32 + chunk) * 4096 + (d >> 5) * 2048 +
                   kc * 512 + (hf * 32 + (d & 31)) * 8 + j0) = pk;
      }
    }
}

// ---------------------------------------------------------------------------
// Stage-2 GEMM: C[M,N] = A[M,K] * B[N,K]^T
// ---------------------------------------------------------------------------
__global__ __launch_bounds__(256) void gemm_bt(const float* __restrict__ A,
                                               const float* __restrict__ Bm,
                                               float* __restrict__ C,
                                               int M, int N, int K) {
  __shared__ __align__(16) __bf16 sA[128][40];
  __shared__ __align__(16) __bf16 sB[128][40];
  const int tid = threadIdx.x;
  const int m0 = blockIdx.y * 128, n0 = blockIdx.x * 128;
  const int lane = tid & 63, w = tid >> 6;
  const int wr = w >> 1, wc = w & 1;
  const int fr = lane & 15;
  const int ko = (lane >> 4) << 3;
  f32x4 acc[4][4] = {};
  for (int k0 = 0; k0 < K; k0 += 32) {
#pragma unroll
    for (int i = 0; i < 4; ++i) {
      int f = tid + (i << 8);
      int row = f >> 3, c4 = (f & 7) << 2;
      f32x4 av = *(const f32x4*)(A + (size_t)(m0 + row) * K + k0 + c4);
      f32x4 bv = *(const f32x4*)(Bm + (size_t)(n0 + row) * K + k0 + c4);
      bf16x4 ah, bh;
#pragma unroll
      for (int j = 0; j < 4; ++j) { ah[j] = (__bf16)av[j]; bh[j] = (__bf16)bv[j]; }
      *(bf16x4*)&sA[row][c4] = ah;
      *(bf16x4*)&sB[row][c4] = bh;
    }
    __syncthreads();
    bf16x8 a[4], b[4];
#pragma unroll
    for (int m = 0; m < 4; ++m) a[m] = *(const bf16x8*)&sA[wr * 64 + m * 16 + fr][ko];
#pragma unroll
    for (int n = 0; n < 4; ++n) b[n] = *(const bf16x8*)&sB[wc * 64 + n * 16 + fr][ko];
#pragma unroll
    for (int m = 0; m < 4; ++m)
#pragma unroll
      for (int n = 0; n < 4; ++n)
        acc[m][n] = __builtin_amdgcn_mfma_f32_16x16x32_bf16(a[m], b[n], acc[m][n], 0, 0, 0);
    __syncthreads();
  }
  const int orow = (lane >> 4) << 2, ocol = lane & 15;
#pragma unroll
  for (int m = 0; m < 4; ++m)
#pragma unroll
    for (int n = 0; n < 4; ++n) {
      int r = m0 + wr * 64 + m * 16 + orow;
      int c = n0 + wc * 64 + n * 16 + ocol;
#pragma unroll
      for (int j = 0; j < 4; ++j) C[(size_t)(r + j) * N + c] = acc[m][n][j];
    }
}

// ---------------------------------------------------------------------------
// touch_k: pull Qp/Kp/Vp lines into the L2 of the XCD whose corr/conv blocks
// will read them (same id&7 -> 3-bh mapping). Pure reads, kept alive via asm.
// grid = 288 = 8 xcd-slots x 36 segs of 64KB (covers 3x6.29MB exactly).
// ---------------------------------------------------------------------------
__global__ __launch_bounds__(256) void touch_k(const __bf16* __restrict__ Qp,
                                               const __bf16* __restrict__ Kp,
                                               const __bf16* __restrict__ Vp) {
  const int id = blockIdx.x;
  const int xcd = id & 7, sub = id >> 3;  // sub in [0,36)
  const int bh0 = xcd * 3;
  const __bf16* base = (sub < 12) ? Qp : (sub < 24) ? Kp : Vp;
  const int seg = sub % 12;  // 64KB segment within this slot's 768KB region
  const f32x4* p = (const f32x4*)(base + (size_t)bh0 * 131072 + (size_t)seg * 32768);
  const int tid = threadIdx.x;
  float s = 0.f;
#pragma unroll
  for (int i = 0; i < 16; ++i) {
    f32x4 v = p[tid + (i << 8)];
    s += v[0] + v[1] + v[2] + v[3];
  }
  asm volatile("" ::"v"(s));  // keep loads live, no side effects
}

// ---------------------------------------------------------------------------
// corr: diagonal-band MFMA, coalesced packed frag loads, register double-
// buffer + rolling-K. grid = 864 = 8 XCD x (3 bh x 36 (qb,tc) pairs).
// ---------------------------------------------------------------------------
__global__ __launch_bounds__(256) void corr_k(const __bf16* __restrict__ Qp,
                                              const __bf16* __restrict__ Kp,
                                              float* __restrict__ P) {
  __shared__ float swc[4][128];
  const int tid = threadIdx.x;
  int id = blockIdx.x;
  int sub = id >> 3;
  const int bh = (id & 7) * 3 + sub / 36;
  const int pi = sub % 36;
  int x = pi, qb = 0;
  while (x >= 8 - qb) { x -= 8 - qb; ++qb; }
  const int tc = qb + x;
  const int lane = tid & 63, w = tid >> 6;

  for (int i = tid; i < 512; i += 256) ((float*)swc)[i] = 0.f;

  const __bf16* qp = Qp + ((size_t)bh << 17) + (lane << 3);
  const __bf16* kp = Kp + ((size_t)bh << 17) + (lane << 3);
  const int qA = 8 * qb + 2 * w;
  f32x16 acc0 = {}, acc1 = {};
  const bf16x8 zf = {};
  bf16x8 Af[2][4], Kc[2][4], Kpv[4];

  {  // prologue: ti = 8tc frags + prev-K frag
    const int t0 = 8 * tc;
#pragma unroll
    for (int kc = 0; kc < 4; ++kc) Af[0][kc] = *(const bf16x8*)(qp + t0 * 2048 + kc * 512);
    const int s0 = t0 - qA, sm = s0 - 1;
#pragma unroll
    for (int kc = 0; kc < 4; ++kc) {
      Kc[0][kc] = (s0 >= 0) ? *(const bf16x8*)(kp + s0 * 2048 + kc * 512) : zf;
      Kpv[kc] = (sm >= 0) ? *(const bf16x8*)(kp + sm * 2048 + kc * 512) : zf;
    }
  }
#pragma unroll
  for (int ii = 0; ii < 8; ++ii) {
    const int cur = ii & 1, nxt = cur ^ 1;
    if (ii < 7) {
      const int tn = 8 * tc + ii + 1;
      const int sn = tn - qA;
#pragma unroll
      for (int kc = 0; kc < 4; ++kc) {
        Af[nxt][kc] = *(const bf16x8*)(qp + tn * 2048 + kc * 512);
        Kc[nxt][kc] = (sn >= 0) ? *(const bf16x8*)(kp + sn * 2048 + kc * 512) : zf;
      }
    }
#pragma unroll
    for (int kc = 0; kc < 4; ++kc) {
      acc0 = __builtin_amdgcn_mfma_f32_32x32x16_bf16(Af[cur][kc], Kc[cur][kc], acc0, 0, 0, 0);
      acc1 = __builtin_amdgcn_mfma_f32_32x32x16_bf16(Af[cur][kc], Kpv[kc], acc1, 0, 0, 0);
    }
#pragma unroll
    for (int kc = 0; kc < 4; ++kc) Kpv[kc] = Kc[cur][kc];
  }

  __syncthreads();
  const int col = lane & 31, rb = (lane >> 5) << 2;
#pragma unroll
  for (int j = 0; j < 16; ++j) {
    int row = (j & 3) + ((j >> 2) << 3) + rb;
    atomicAdd(&swc[w][row - col + 31], acc0[j]);   // band qA
    atomicAdd(&swc[w][row - col + 63], acc1[j]);   // band qA+1
  }
  __syncthreads();

  // merge wave regions; write FULL row of unique slice pi (zeros elsewhere)
  float* Pd = P + ((size_t)pi * BH_ + bh) * T_;
  float ov[8];
#pragma unroll
  for (int u = 0; u < 8; ++u) {
    int L = (tid << 3) + u;
    int l = L - 256 * qb;
    float s = 0.f;
    if (l >= -31 && l < 256) {
#pragma unroll
      for (int ww = 0; ww < 4; ++ww) {
        int r = l - 64 * ww + 31;
        if (r >= 0 && r < 95) s += swc[ww][r];
      }
    }
    ov[u] = s;
  }
  *(f32x4*)(Pd + (tid << 3)) = *(f32x4*)&ov[0];
  *(f32x4*)(Pd + (tid << 3) + 4) = *(f32x4*)&ov[4];
}

// ---------------------------------------------------------------------------
// soft_k: reduce 36 partial slices -> Rb (8 phase-shifted reversed-e, bf16)
// and zinv = 1/Z.
// ---------------------------------------------------------------------------
__global__ __launch_bounds__(256) void soft_k(const float* __restrict__ P,
                                              const float* __restrict__ temp,
                                              __bf16* __restrict__ Rb,
                                              float* __restrict__ zinv) {
  __shared__ float se[T_];
  __shared__ float lm[4], wsum[4];
  const int bh = blockIdx.x, tid = threadIdx.x;
  const int lane = tid & 63, wid = tid >> 6;
  const float scale = 1.0f / (64.0f * (temp[0] + 1e-6f));
  f32x4 sa = {}, sb = {};
#pragma unroll
  for (int j = 0; j < 36; ++j) {
    const float* pp = P + ((size_t)j * BH_ + bh) * T_ + (tid << 3);
    sa += *(const f32x4*)pp;
    sb += *(const f32x4*)(pp + 4);
  }
  float v[8];
#pragma unroll
  for (int i = 0; i < 4; ++i) { v[i] = sa[i] * scale; v[4 + i] = sb[i] * scale; }
  float m = v[0];
#pragma unroll
  for (int i = 1; i < 8; ++i) m = fmaxf(m, v[i]);
#pragma unroll
  for (int off = 1; off < 64; off <<= 1) m = fmaxf(m, __shfl_xor(m, off));
  if (lane == 0) lm[wid] = m;
  __syncthreads();
  m = fmaxf(fmaxf(lm[0], lm[1]), fmaxf(lm[2], lm[3]));
  float ex[8], pr[8], run = 0;
#pragma unroll
  for (int i = 0; i < 8; ++i) { ex[i] = __expf(v[i] - m); run += ex[i]; pr[i] = run; }
  float s = run;
  for (int off = 1; off < 64; off <<= 1) {
    float o = __shfl_up(s, off);
    if (lane >= off) s += o;
  }
  if (lane == 63) wsum[wid] = s;
  __syncthreads();
  float base = s - run;
  for (int jw = 0; jw < wid; ++jw) base += wsum[jw];
#pragma unroll
  for (int i = 0; i < 8; ++i) {
    int t = (tid << 3) + i;
    zinv[(size_t)bh * T_ + t] = 1.0f / (base + pr[i]);
    se[t] = ex[i];
  }
  __syncthreads();
  __bf16* rb = Rb + (size_t)bh * 8 * RSTR;
  for (int c = tid; c < RSTR / 8; c += 256) {
    int i0 = c << 3;
#pragma unroll
    for (int p = 0; p < 8; ++p) {
      bf16x8 ovv;
#pragma unroll
      for (int e = 0; e < 8; ++e) {
        int idx = T_ - 1 - p - (i0 + e);
        ovv[e] = (__bf16)((idx >= 0) ? se[idx] : 0.f);
      }
      *(bf16x8*)(rb + p * RSTR + i0) = ovv;
    }
  }
}

// ---------------------------------------------------------------------------
// conv: Toeplitz MFMA, triple-buffered V-chunk pipeline (prefetch distance 3).
// A-frags from LDS reversed-e; B-frags coalesced from packed Vp.
// grid = 384 = 8 x (3 bh x 16 pairs), paired t-blocks {i,31-i} load-balance.
// ---------------------------------------------------------------------------
__global__ __launch_bounds__(256) void conv_k(const __bf16* __restrict__ Vp,
                                              const __bf16* __restrict__ Rb,
                                              const float* __restrict__ zinv,
                                              float* __restrict__ y2) {
  __shared__ __align__(16) __bf16 revc[8 * RSTR];
  const int tid = threadIdx.x;
  int id = blockIdx.x;
  int sub = id >> 3;
  const int bh = (id & 7) * 3 + (sub >> 4);
  const int pr = sub & 15;
  const int lane = tid & 63, w = tid >> 6;

  const __bf16* rb = Rb + (size_t)bh * 8 * RSTR;
  for (int c = tid; c < RSTR; c += 256)
    *(bf16x8*)&revc[c << 3] = *(const bf16x8*)(rb + ((size_t)c << 3));
  __syncthreads();

  const int fr = lane & 31, kg = (lane >> 5) << 3;
  const int tt = (w < 2) ? (64 * pr + 32 * w) : (64 * (31 - pr) + 32 * (w - 2));
  const int trow = tt + fr;
  const int pp = (T_ - 1 - trow) & 7;
  const int obase = (T_ - 1 - trow) - pp;
  const __bf16* vpb = Vp + (size_t)bh * 131072 + (lane << 3);
  f32x16 acc0 = {}, acc1 = {};
  const int nst = (tt >> 6) + 1;

  bf16x8 A00, A01, A02, A03, A10, A11, A12, A13;
  bf16x8 B00, B01, B02, B03, B10, B11, B12, B13;
  bf16x8 C00, C01, C02, C03, C10, C11, C12, C13;

#define LOADV(P, CH)                                                          \
  {                                                                           \
    const __bf16* vb_ = vpb + (size_t)(CH) * 4096;                            \
    P##00 = *(const bf16x8*)(vb_);          P##01 = *(const bf16x8*)(vb_ + 512);  \
    P##02 = *(const bf16x8*)(vb_ + 1024);   P##03 = *(const bf16x8*)(vb_ + 1536); \
    P##10 = *(const bf16x8*)(vb_ + 2048);   P##11 = *(const bf16x8*)(vb_ + 2560); \
    P##12 = *(const bf16x8*)(vb_ + 3072);   P##13 = *(const bf16x8*)(vb_ + 3584); \
  }
#define MSTEP(P, ST)                                                          \
  {                                                                           \
    const int ab_ = pp * RSTR + obase + (ST) * 64 + kg;                       \
    bf16x8 a0_ = *(const bf16x8*)&revc[ab_];                                  \
    bf16x8 a1_ = *(const bf16x8*)&revc[ab_ + 16];                             \
    bf16x8 a2_ = *(const bf16x8*)&revc[ab_ + 32];                             \
    bf16x8 a3_ = *(const bf16x8*)&revc[ab_ + 48];                             \
    acc0 = __builtin_amdgcn_mfma_f32_32x32x16_bf16(a0_, P##00, acc0, 0, 0, 0);\
    acc1 = __builtin_amdgcn_mfma_f32_32x32x16_bf16(a0_, P##10, acc1, 0, 0, 0);\
    acc0 = __builtin_amdgcn_mfma_f32_32x32x16_bf16(a1_, P##01, acc0, 0, 0, 0);\
    acc1 = __builtin_amdgcn_mfma_f32_32x32x16_bf16(a1_, P##11, acc1, 0, 0, 0);\
    acc0 = __builtin_amdgcn_mfma_f32_32x32x16_bf16(a2_, P##02, acc0, 0, 0, 0);\
    acc1 = __builtin_amdgcn_mfma_f32_32x32x16_bf16(a2_, P##12, acc1, 0, 0, 0);\
    acc0 = __builtin_amdgcn_mfma_f32_32x32x16_bf16(a3_, P##03, acc0, 0, 0, 0);\
    acc1 = __builtin_amdgcn_mfma_f32_32x32x16_bf16(a3_, P##13, acc1, 0, 0, 0);\
  }

  LOADV(A, 0);
  if (nst > 1) LOADV(B, 1);
  if (nst > 2) LOADV(C, 2);
  int st = 0;
  while (true) {
    MSTEP(A, st); if (st + 3 < nst) LOADV(A, st + 3); if (++st >= nst) break;
    MSTEP(B, st); if (st + 3 < nst) LOADV(B, st + 3); if (++st >= nst) break;
    MSTEP(C, st); if (st + 3 < nst) LOADV(C, st + 3); if (++st >= nst) break;
  }
#undef LOADV
#undef MSTEP

  const int b = bh / H_, h = bh % H_;
  const int ocol = lane & 31, rbj = (lane >> 5) << 2;
  const float* zp = zinv + (size_t)bh * T_;
#pragma unroll
  for (int j = 0; j < 16; ++j) {
    int row = (j & 3) + ((j >> 2) << 3) + rbj;
    int t = tt + row;
    float zi = zp[t];
    float* yr = y2 + ((size_t)b * T_ + t) * C_ + h * 64;
    yr[ocol] = acc0[j] * zi;
    yr[32 + ocol] = acc1[j] * zi;
  }
}

// ---------------------------------------------------------------------------
extern "C" void kernel_launch(void* const* d_in, const int* in_sizes, int n_in,
                              void* d_out, int out_size, void* d_ws, size_t ws_size,
                              hipStream_t stream) {
  const float* x = (const float*)d_in[0];
  const float* c_attn = (const float*)d_in[1];
  const float* c_proj = (const float*)d_in[2];
  const float* temp = (const float*)d_in[3];
  float* out = (float*)d_out;

  // ws: Qp|Kp|Vp (3 x 3.145M bf16) | Rb | zinv | y2 | P36  (~39.7 MB)
  __bf16* Qp = (__bf16*)d_ws;
  __bf16* Kp = Qp + (size_t)BH_ * 64 * 2048;
  __bf16* Vp = Kp + (size_t)BH_ * 64 * 2048;
  __bf16* Rb = Vp + (size_t)BH_ * 32 * 4096;
  float* zinv = (float*)(Rb + (size_t)BH_ * 8 * RSTR);
  float* y2 = zinv + (size_t)BH_ * T_;
  float* P = y2 + (size_t)M_ * C_;

  gemm_qkv<<<dim3(2304 / 128, M_ / 128), 256, 0, stream>>>(x, c_attn, Qp, Kp, Vp);
  touch_k<<<dim3(288), 256, 0, stream>>>(Qp, Kp, Vp);
  corr_k<<<dim3(864), 256, 0, stream>>>(Qp, Kp, P);
  soft_k<<<dim3(BH_), 256, 0, stream>>>(P, temp, Rb, zinv);
  conv_k<<<dim3(384), 256, 0, stream>>>(Vp, Rb, zinv, y2);
  gemm_bt<<<dim3(C_ / 128, M_ / 128), 256, 0, stream>>>(y2, c_proj, out, M_, C_, C_);
}

// Round 7
// 128.955 us; speedup vs baseline: 1.2411x; 1.2411x over previous
//
#include <hip/hip_runtime.h>

#define T_ 2048
#define B_ 2
#define H_ 12
#define C_ 768
#define M_ 4096  // B*T
#define BH_ (B_ * H_)
#define RSTR 2200  // reversed-e padded stride

typedef __attribute__((ext_vector_type(4))) float f32x4;
typedef __attribute__((ext_vector_type(16))) float f32x16;
typedef __attribute__((ext_vector_type(8))) __bf16 bf16x8;
typedef __attribute__((ext_vector_type(4))) __bf16 bf16x4;

// Packed fragment-major layouts (coalesced MFMA frag loads: addr = base + lane*8 elems):
//  Qp/Kp: [bh][tile=t>>5][kc=d>>4][lane=((d>>3)&1)*32 + (t&31)][j=d&7]   (tile stride 2048)
//  Vp:    [bh][chunk=t>>6][dhalf=d>>5][kc=(t&63)>>4][lane=(((t&63)>>3)&1)*32 + (d&31)][j=t&7]

// ---------------------------------------------------------------------------
// Stage-1 GEMM: qkv = x @ c_attn^T -> packed bf16 Qp, Kp, Vp
// ---------------------------------------------------------------------------
__global__ __launch_bounds__(256) void gemm_qkv(const float* __restrict__ A,
                                                const float* __restrict__ Bm,
                                                __bf16* __restrict__ Qp,
                                                __bf16* __restrict__ Kp,
                                                __bf16* __restrict__ Vp) {
  __shared__ __align__(16) __bf16 sA[128][40];
  __shared__ __align__(16) __bf16 sB[128][40];
  const int tid = threadIdx.x;
  const int m0 = blockIdx.y * 128, n0 = blockIdx.x * 128;
  const int lane = tid & 63, w = tid >> 6;
  const int wr = w >> 1, wc = w & 1;
  const int fr = lane & 15;
  const int ko = (lane >> 4) << 3;
  const int K = C_;
  f32x4 acc[4][4] = {};
  for (int k0 = 0; k0 < K; k0 += 32) {
#pragma unroll
    for (int i = 0; i < 4; ++i) {
      int f = tid + (i << 8);
      int row = f >> 3, c4 = (f & 7) << 2;
      f32x4 av = *(const f32x4*)(A + (size_t)(m0 + row) * K + k0 + c4);
      f32x4 bv = *(const f32x4*)(Bm + (size_t)(n0 + row) * K + k0 + c4);
      bf16x4 ah, bh;
#pragma unroll
      for (int j = 0; j < 4; ++j) { ah[j] = (__bf16)av[j]; bh[j] = (__bf16)bv[j]; }
      *(bf16x4*)&sA[row][c4] = ah;
      *(bf16x4*)&sB[row][c4] = bh;
    }
    __syncthreads();
    bf16x8 a[4], b[4];
#pragma unroll
    for (int m = 0; m < 4; ++m) a[m] = *(const bf16x8*)&sA[wr * 64 + m * 16 + fr][ko];
#pragma unroll
    for (int n = 0; n < 4; ++n) b[n] = *(const bf16x8*)&sB[wc * 64 + n * 16 + fr][ko];
#pragma unroll
    for (int m = 0; m < 4; ++m)
#pragma unroll
      for (int n = 0; n < 4; ++n)
        acc[m][n] = __builtin_amdgcn_mfma_f32_16x16x32_bf16(a[m], b[n], acc[m][n], 0, 0, 0);
    __syncthreads();
  }
  const int orow = (lane >> 4) << 2, ocol = lane & 15;
#pragma unroll
  for (int m = 0; m < 4; ++m)
#pragma unroll
    for (int n = 0; n < 4; ++n) {
      int r = m0 + wr * 64 + m * 16 + orow;  // token (4 consecutive via j)
      int c = n0 + wc * 64 + n * 16 + ocol;  // feature
      int sec = c / 768;
      int hd = c - sec * 768;
      int h = hd >> 6, d = hd & 63;
      int b = r >> 11, t = r & 2047;
      int bh = b * H_ + h;
      if (sec < 2) {
        int tile = t >> 5, rr = t & 31;
        int kc = d >> 4, half = (d >> 3) & 1, dj = d & 7;
        __bf16* dst = (sec == 0 ? Qp : Kp) + ((size_t)bh * 64 + tile) * 2048 +
                      kc * 512 + (half * 32 + rr) * 8 + dj;
#pragma unroll
        for (int j = 0; j < 4; ++j) dst[j * 8] = (__bf16)acc[m][n][j];  // rr+j
      } else {
        int chunk = t >> 6, sk = t & 63;
        int kc = sk >> 4, hf = (sk >> 3) & 1, j0 = sk & 7;  // j0 in {0,4}
        bf16x4 pk;
#pragma unroll
        for (int j = 0; j < 4; ++j) pk[j] = (__bf16)acc[m][n][j];
        *(bf16x4*)(Vp + ((size_t)bh * 32 + chunk) * 4096 + (d >> 5) * 2048 +
                   kc * 512 + (hf * 32 + (d & 31)) * 8 + j0) = pk;
      }
    }
}

// ---------------------------------------------------------------------------
// Stage-2 GEMM: C[M,N] = A[M,K] * B[N,K]^T
// ---------------------------------------------------------------------------
__global__ __launch_bounds__(256) void gemm_bt(const float* __restrict__ A,
                                               const float* __restrict__ Bm,
                                               float* __restrict__ C,
                                               int M, int N, int K) {
  __shared__ __align__(16) __bf16 sA[128][40];
  __shared__ __align__(16) __bf16 sB[128][40];
  const int tid = threadIdx.x;
  const int m0 = blockIdx.y * 128, n0 = blockIdx.x * 128;
  const int lane = tid & 63, w = tid >> 6;
  const int wr = w >> 1, wc = w & 1;
  const int fr = lane & 15;
  const int ko = (lane >> 4) << 3;
  f32x4 acc[4][4] = {};
  for (int k0 = 0; k0 < K; k0 += 32) {
#pragma unroll
    for (int i = 0; i < 4; ++i) {
      int f = tid + (i << 8);
      int row = f >> 3, c4 = (f & 7) << 2;
      f32x4 av = *(const f32x4*)(A + (size_t)(m0 + row) * K + k0 + c4);
      f32x4 bv = *(const f32x4*)(Bm + (size_t)(n0 + row) * K + k0 + c4);
      bf16x4 ah, bh;
#pragma unroll
      for (int j = 0; j < 4; ++j) { ah[j] = (__bf16)av[j]; bh[j] = (__bf16)bv[j]; }
      *(bf16x4*)&sA[row][c4] = ah;
      *(bf16x4*)&sB[row][c4] = bh;
    }
    __syncthreads();
    bf16x8 a[4], b[4];
#pragma unroll
    for (int m = 0; m < 4; ++m) a[m] = *(const bf16x8*)&sA[wr * 64 + m * 16 + fr][ko];
#pragma unroll
    for (int n = 0; n < 4; ++n) b[n] = *(const bf16x8*)&sB[wc * 64 + n * 16 + fr][ko];
#pragma unroll
    for (int m = 0; m < 4; ++m)
#pragma unroll
      for (int n = 0; n < 4; ++n)
        acc[m][n] = __builtin_amdgcn_mfma_f32_16x16x32_bf16(a[m], b[n], acc[m][n], 0, 0, 0);
    __syncthreads();
  }
  const int orow = (lane >> 4) << 2, ocol = lane & 15;
#pragma unroll
  for (int m = 0; m < 4; ++m)
#pragma unroll
    for (int n = 0; n < 4; ++n) {
      int r = m0 + wr * 64 + m * 16 + orow;
      int c = n0 + wc * 64 + n * 16 + ocol;
#pragma unroll
      for (int j = 0; j < 4; ++j) C[(size_t)(r + j) * N + c] = acc[m][n][j];
    }
}

// ---------------------------------------------------------------------------
// corr_mfma: ABLATED corr — loads + MFMA only. No LDS, no barriers, no
// atomics. Each wave writes its two raw 32x32 accumulator tiles (bf16,
// coalesced [b01][j][lane]) to Cw[(bh*36+pi)*8 + w*2 + b01][1024].
// grid = 864 = 8 XCD x (3 bh x 36 (qb,tc) pairs).
// ---------------------------------------------------------------------------
__global__ __launch_bounds__(256) void corr_mfma(const __bf16* __restrict__ Qp,
                                                 const __bf16* __restrict__ Kp,
                                                 __bf16* __restrict__ Cw) {
  const int tid = threadIdx.x;
  int id = blockIdx.x;
  int sub = id >> 3;
  const int bh = (id & 7) * 3 + sub / 36;
  const int pi = sub % 36;
  int x = pi, qb = 0;
  while (x >= 8 - qb) { x -= 8 - qb; ++qb; }
  const int tc = qb + x;
  const int lane = tid & 63, w = tid >> 6;

  const __bf16* qp = Qp + ((size_t)bh << 17) + (lane << 3);
  const __bf16* kp = Kp + ((size_t)bh << 17) + (lane << 3);
  const int qA = 8 * qb + 2 * w;
  f32x16 acc0 = {}, acc1 = {};
  const bf16x8 zf = {};
  bf16x8 Af[2][4], Kc[2][4], Kpv[4];

  {  // prologue
    const int t0 = 8 * tc;
#pragma unroll
    for (int kc = 0; kc < 4; ++kc) Af[0][kc] = *(const bf16x8*)(qp + t0 * 2048 + kc * 512);
    const int s0 = t0 - qA, sm = s0 - 1;
#pragma unroll
    for (int kc = 0; kc < 4; ++kc) {
      Kc[0][kc] = (s0 >= 0) ? *(const bf16x8*)(kp + s0 * 2048 + kc * 512) : zf;
      Kpv[kc] = (sm >= 0) ? *(const bf16x8*)(kp + sm * 2048 + kc * 512) : zf;
    }
  }
#pragma unroll
  for (int ii = 0; ii < 8; ++ii) {
    const int cur = ii & 1, nxt = cur ^ 1;
    if (ii < 7) {
      const int tn = 8 * tc + ii + 1;
      const int sn = tn - qA;
#pragma unroll
      for (int kc = 0; kc < 4; ++kc) {
        Af[nxt][kc] = *(const bf16x8*)(qp + tn * 2048 + kc * 512);
        Kc[nxt][kc] = (sn >= 0) ? *(const bf16x8*)(kp + sn * 2048 + kc * 512) : zf;
      }
    }
#pragma unroll
    for (int kc = 0; kc < 4; ++kc) {
      acc0 = __builtin_amdgcn_mfma_f32_32x32x16_bf16(Af[cur][kc], Kc[cur][kc], acc0, 0, 0, 0);
      acc1 = __builtin_amdgcn_mfma_f32_32x32x16_bf16(Af[cur][kc], Kpv[kc], acc1, 0, 0, 0);
    }
#pragma unroll
    for (int kc = 0; kc < 4; ++kc) Kpv[kc] = Kc[cur][kc];
  }

  // raw tile dump: [tile][j][lane] bf16, fully coalesced (128B per store instr)
  __bf16* o = Cw + (((size_t)(bh * 36 + pi) * 4 + w) * 2) * 1024 + lane;
#pragma unroll
  for (int j = 0; j < 16; ++j) {
    o[j * 64] = (__bf16)acc0[j];
    o[1024 + j * 64] = (__bf16)acc1[j];
  }
}

// ---------------------------------------------------------------------------
// corr_red: diagonal-reduce the raw tiles. grid = 288 = 12 groups x 24 bh.
// Each block: 3 pairs x 4 waves x 2 bands; wave w stages its tile to LDS
// [32][33] (conflict-free), predicated diag sums (63 lanes), accumulates
// into a per-wave non-atomic P-row, merges to P12[g][bh][T].
// ---------------------------------------------------------------------------
__global__ __launch_bounds__(256) void corr_red(const __bf16* __restrict__ Cw,
                                                float* __restrict__ P12) {
  __shared__ float tile[4][1056];   // [w][row*33+col]
  __shared__ float prow[4][2112];   // [w][lag+32]
  const int id = blockIdx.x;
  const int bh = id % 24, g = id / 24;
  const int tid = threadIdx.x, lane = tid & 63, w = tid >> 6;

  for (int i = tid; i < 4 * 2112; i += 256) ((float*)prow)[i] = 0.f;
  __syncthreads();

  const int col = lane & 31, hi = lane >> 5;
#pragma unroll
  for (int pp = 0; pp < 3; ++pp) {
    const int pi = g * 3 + pp;
    int x = pi, qb = 0;
    while (x >= 8 - qb) { x -= 8 - qb; ++qb; }
#pragma unroll
    for (int b01 = 0; b01 < 2; ++b01) {
      const __bf16* src =
          Cw + (((size_t)(bh * 36 + pi) * 4 + w) * 2 + b01) * 1024 + lane;
      float v[16];
#pragma unroll
      for (int j = 0; j < 16; ++j) v[j] = (float)src[j * 64];
#pragma unroll
      for (int j = 0; j < 16; ++j) {
        int row = (j & 3) + ((j >> 2) << 3) + 4 * hi;
        tile[w][row * 33 + col] = v[j];
      }
      __syncthreads();
      if (lane < 63) {
        const int d = lane - 31;
        float s = 0.f;
#pragma unroll
        for (int c = 0; c < 32; ++c) {
          int r = c + d;
          bool ok = (unsigned)r < 32u;
          float val = tile[w][(ok ? r : 0) * 33 + c];
          s += ok ? val : 0.f;
        }
        const int qA = 8 * qb + 2 * w + b01;
        prow[w][32 * qA + d + 32] += s;
      }
      __syncthreads();
    }
  }

  float* out = P12 + ((size_t)g * BH_ + bh) * T_;
  float ov[8];
#pragma unroll
  for (int u = 0; u < 8; ++u) {
    int L = (tid << 3) + u;
    ov[u] = prow[0][L + 32] + prow[1][L + 32] + prow[2][L + 32] + prow[3][L + 32];
  }
  *(f32x4*)(out + (tid << 3)) = *(f32x4*)&ov[0];
  *(f32x4*)(out + (tid << 3) + 4) = *(f32x4*)&ov[4];
}

// ---------------------------------------------------------------------------
// soft_k: reduce 12 partial slices -> Rb (8 phase-shifted reversed-e, bf16)
// and zinv = 1/Z.
// ---------------------------------------------------------------------------
__global__ __launch_bounds__(256) void soft_k(const float* __restrict__ P,
                                              const float* __restrict__ temp,
                                              __bf16* __restrict__ Rb,
                                              float* __restrict__ zinv) {
  __shared__ float se[T_];
  __shared__ float lm[4], wsum[4];
  const int bh = blockIdx.x, tid = threadIdx.x;
  const int lane = tid & 63, wid = tid >> 6;
  const float scale = 1.0f / (64.0f * (temp[0] + 1e-6f));
  f32x4 sa = {}, sb = {};
#pragma unroll
  for (int j = 0; j < 12; ++j) {
    const float* pp = P + ((size_t)j * BH_ + bh) * T_ + (tid << 3);
    sa += *(const f32x4*)pp;
    sb += *(const f32x4*)(pp + 4);
  }
  float v[8];
#pragma unroll
  for (int i = 0; i < 4; ++i) { v[i] = sa[i] * scale; v[4 + i] = sb[i] * scale; }
  float m = v[0];
#pragma unroll
  for (int i = 1; i < 8; ++i) m = fmaxf(m, v[i]);
#pragma unroll
  for (int off = 1; off < 64; off <<= 1) m = fmaxf(m, __shfl_xor(m, off));
  if (lane == 0) lm[wid] = m;
  __syncthreads();
  m = fmaxf(fmaxf(lm[0], lm[1]), fmaxf(lm[2], lm[3]));
  float ex[8], pr[8], run = 0;
#pragma unroll
  for (int i = 0; i < 8; ++i) { ex[i] = __expf(v[i] - m); run += ex[i]; pr[i] = run; }
  float s = run;
  for (int off = 1; off < 64; off <<= 1) {
    float o = __shfl_up(s, off);
    if (lane >= off) s += o;
  }
  if (lane == 63) wsum[wid] = s;
  __syncthreads();
  float base = s - run;
  for (int jw = 0; jw < wid; ++jw) base += wsum[jw];
#pragma unroll
  for (int i = 0; i < 8; ++i) {
    int t = (tid << 3) + i;
    zinv[(size_t)bh * T_ + t] = 1.0f / (base + pr[i]);
    se[t] = ex[i];
  }
  __syncthreads();
  __bf16* rb = Rb + (size_t)bh * 8 * RSTR;
  for (int c = tid; c < RSTR / 8; c += 256) {
    int i0 = c << 3;
#pragma unroll
    for (int p = 0; p < 8; ++p) {
      bf16x8 ovv;
#pragma unroll
      for (int e = 0; e < 8; ++e) {
        int idx = T_ - 1 - p - (i0 + e);
        ovv[e] = (__bf16)((idx >= 0) ? se[idx] : 0.f);
      }
      *(bf16x8*)(rb + p * RSTR + i0) = ovv;
    }
  }
}

// ---------------------------------------------------------------------------
// conv: Toeplitz MFMA, triple-buffered V-chunk pipeline (prefetch distance 3).
// A-frags from LDS reversed-e; B-frags coalesced from packed Vp.
// grid = 384 = 8 x (3 bh x 16 pairs), paired t-blocks {i,31-i} load-balance.
// ---------------------------------------------------------------------------
__global__ __launch_bounds__(256) void conv_k(const __bf16* __restrict__ Vp,
                                              const __bf16* __restrict__ Rb,
                                              const float* __restrict__ zinv,
                                              float* __restrict__ y2) {
  __shared__ __align__(16) __bf16 revc[8 * RSTR];
  const int tid = threadIdx.x;
  int id = blockIdx.x;
  int sub = id >> 3;
  const int bh = (id & 7) * 3 + (sub >> 4);
  const int pr = sub & 15;
  const int lane = tid & 63, w = tid >> 6;

  const __bf16* rb = Rb + (size_t)bh * 8 * RSTR;
  for (int c = tid; c < RSTR; c += 256)
    *(bf16x8*)&revc[c << 3] = *(const bf16x8*)(rb + ((size_t)c << 3));
  __syncthreads();

  const int fr = lane & 31, kg = (lane >> 5) << 3;
  const int tt = (w < 2) ? (64 * pr + 32 * w) : (64 * (31 - pr) + 32 * (w - 2));
  const int trow = tt + fr;
  const int pp = (T_ - 1 - trow) & 7;
  const int obase = (T_ - 1 - trow) - pp;
  const __bf16* vpb = Vp + (size_t)bh * 131072 + (lane << 3);
  f32x16 acc0 = {}, acc1 = {};
  const int nst = (tt >> 6) + 1;

  bf16x8 A00, A01, A02, A03, A10, A11, A12, A13;
  bf16x8 B00, B01, B02, B03, B10, B11, B12, B13;
  bf16x8 C00, C01, C02, C03, C10, C11, C12, C13;

#define LOADV(P, CH)                                                          \
  {                                                                           \
    const __bf16* vb_ = vpb + (size_t)(CH) * 4096;                            \
    P##00 = *(const bf16x8*)(vb_);          P##01 = *(const bf16x8*)(vb_ + 512);  \
    P##02 = *(const bf16x8*)(vb_ + 1024);   P##03 = *(const bf16x8*)(vb_ + 1536); \
    P##10 = *(const bf16x8*)(vb_ + 2048);   P##11 = *(const bf16x8*)(vb_ + 2560); \
    P##12 = *(const bf16x8*)(vb_ + 3072);   P##13 = *(const bf16x8*)(vb_ + 3584); \
  }
#define MSTEP(P, ST)                                                          \
  {                                                                           \
    const int ab_ = pp * RSTR + obase + (ST) * 64 + kg;                       \
    bf16x8 a0_ = *(const bf16x8*)&revc[ab_];                                  \
    bf16x8 a1_ = *(const bf16x8*)&revc[ab_ + 16];                             \
    bf16x8 a2_ = *(const bf16x8*)&revc[ab_ + 32];                             \
    bf16x8 a3_ = *(const bf16x8*)&revc[ab_ + 48];                             \
    acc0 = __builtin_amdgcn_mfma_f32_32x32x16_bf16(a0_, P##00, acc0, 0, 0, 0);\
    acc1 = __builtin_amdgcn_mfma_f32_32x32x16_bf16(a0_, P##10, acc1, 0, 0, 0);\
    acc0 = __builtin_amdgcn_mfma_f32_32x32x16_bf16(a1_, P##01, acc0, 0, 0, 0);\
    acc1 = __builtin_amdgcn_mfma_f32_32x32x16_bf16(a1_, P##11, acc1, 0, 0, 0);\
    acc0 = __builtin_amdgcn_mfma_f32_32x32x16_bf16(a2_, P##02, acc0, 0, 0, 0);\
    acc1 = __builtin_amdgcn_mfma_f32_32x32x16_bf16(a2_, P##12, acc1, 0, 0, 0);\
    acc0 = __builtin_amdgcn_mfma_f32_32x32x16_bf16(a3_, P##03, acc0, 0, 0, 0);\
    acc1 = __builtin_amdgcn_mfma_f32_32x32x16_bf16(a3_, P##13, acc1, 0, 0, 0);\
  }

  LOADV(A, 0);
  if (nst > 1) LOADV(B, 1);
  if (nst > 2) LOADV(C, 2);
  int st = 0;
  while (true) {
    MSTEP(A, st); if (st + 3 < nst) LOADV(A, st + 3); if (++st >= nst) break;
    MSTEP(B, st); if (st + 3 < nst) LOADV(B, st + 3); if (++st >= nst) break;
    MSTEP(C, st); if (st + 3 < nst) LOADV(C, st + 3); if (++st >= nst) break;
  }
#undef LOADV
#undef MSTEP

  const int b = bh / H_, h = bh % H_;
  const int ocol = lane & 31, rbj = (lane >> 5) << 2;
  const float* zp = zinv + (size_t)bh * T_;
#pragma unroll
  for (int j = 0; j < 16; ++j) {
    int row = (j & 3) + ((j >> 2) << 3) + rbj;
    int t = tt + row;
    float zi = zp[t];
    float* yr = y2 + ((size_t)b * T_ + t) * C_ + h * 64;
    yr[ocol] = acc0[j] * zi;
    yr[32 + ocol] = acc1[j] * zi;
  }
}

// ---------------------------------------------------------------------------
extern "C" void kernel_launch(void* const* d_in, const int* in_sizes, int n_in,
                              void* d_out, int out_size, void* d_ws, size_t ws_size,
                              hipStream_t stream) {
  const float* x = (const float*)d_in[0];
  const float* c_attn = (const float*)d_in[1];
  const float* c_proj = (const float*)d_in[2];
  const float* temp = (const float*)d_in[3];
  float* out = (float*)d_out;

  // ws: Qp|Kp|Vp (18.9MB) | Rb (0.85MB) | zinv (0.2MB) | Cw/y2 aliased
  // (14.2MB; Cw dead before conv writes y2) | P12 (2.4MB)  ~= 36.4 MB
  __bf16* Qp = (__bf16*)d_ws;
  __bf16* Kp = Qp + (size_t)BH_ * 64 * 2048;
  __bf16* Vp = Kp + (size_t)BH_ * 64 * 2048;
  __bf16* Rb = Vp + (size_t)BH_ * 32 * 4096;
  float* zinv = (float*)(Rb + (size_t)BH_ * 8 * RSTR);
  float* y2 = zinv + (size_t)BH_ * T_;
  __bf16* Cw = (__bf16*)y2;  // 24*36*8*1024 bf16, consumed before conv
  float* P12 = (float*)(Cw + (size_t)BH_ * 36 * 8 * 1024);

  gemm_qkv<<<dim3(2304 / 128, M_ / 128), 256, 0, stream>>>(x, c_attn, Qp, Kp, Vp);
  corr_mfma<<<dim3(864), 256, 0, stream>>>(Qp, Kp, Cw);
  corr_red<<<dim3(288), 256, 0, stream>>>(Cw, P12);
  soft_k<<<dim3(BH_), 256, 0, stream>>>(P12, temp, Rb, zinv);
  conv_k<<<dim3(384), 256, 0, stream>>>(Vp, Rb, zinv, y2);
  gemm_bt<<<dim3(C_ / 128, M_ / 128), 256, 0, stream>>>(y2, c_proj, out, M_, C_, C_);
}

// Round 8
// 110.877 us; speedup vs baseline: 1.4435x; 1.1631x over previous
//
#include <hip/hip_runtime.h>

#define T_ 2048
#define B_ 2
#define H_ 12
#define C_ 768
#define M_ 4096  // B*T
#define BH_ (B_ * H_)
#define RSTR 2200  // reversed-e padded stride

typedef __attribute__((ext_vector_type(4))) float f32x4;
typedef __attribute__((ext_vector_type(16))) float f32x16;
typedef __attribute__((ext_vector_type(8))) __bf16 bf16x8;
typedef __attribute__((ext_vector_type(4))) __bf16 bf16x4;

// async global->LDS, 16B per lane; LDS dest wave-uniform base + lane*16
#define GLOAD16(GP, LP)                                                   \
  __builtin_amdgcn_global_load_lds(                                       \
      (__attribute__((address_space(1))) void*)(GP),                      \
      (__attribute__((address_space(3))) void*)(LP), 16, 0, 0)

// Packed fragment-major layouts (coalesced MFMA frag loads):
//  Qp/Kp: [bh][tile=t>>5][kc=d>>4][lane=((d>>3)&1)*32 + (t&31)][j=d&7]
//  Vp:    [bh][chunk=t>>6][dhalf=d>>5][kc=(t&63)>>4][lane=(((t&63)>>3)&1)*32+(d&31)][j=t&7]

// ---------------------------------------------------------------------------
// cvt3: one-shot fp32 -> bf16 for x, c_attn, c_proj.
// grid = 1536 + 864 + 288 = 2688 blocks x 2048 elems.
// ---------------------------------------------------------------------------
__global__ __launch_bounds__(256) void cvt3_k(const float* __restrict__ x,
                                              const float* __restrict__ ca,
                                              const float* __restrict__ cp,
                                              __bf16* __restrict__ xb,
                                              __bf16* __restrict__ wb,
                                              __bf16* __restrict__ pb) {
  const int id = blockIdx.x;
  const float* src;
  __bf16* dst;
  size_t base;
  if (id < 1536) { src = x; dst = xb; base = (size_t)id * 2048; }
  else if (id < 2400) { src = ca; dst = wb; base = (size_t)(id - 1536) * 2048; }
  else { src = cp; dst = pb; base = (size_t)(id - 2400) * 2048; }
  const size_t o = base + (size_t)threadIdx.x * 8;
  f32x4 v0 = *(const f32x4*)(src + o);
  f32x4 v1 = *(const f32x4*)(src + o + 4);
  bf16x8 r;
#pragma unroll
  for (int j = 0; j < 4; ++j) { r[j] = (__bf16)v0[j]; r[4 + j] = (__bf16)v1[j]; }
  *(bf16x8*)(dst + o) = r;
}

// ---------------------------------------------------------------------------
// Stage-1 GEMM (bf16 in): qkv = xb @ wb^T -> packed Qp, Kp, Vp.
// m97 recipe: 128x128 tile, BK=32, global_load_lds(16B), linear LDS,
// 2-barrier K-loop. XCD-swizzled 1D grid of 576.
// ---------------------------------------------------------------------------
__global__ __launch_bounds__(256) void gemm_qkv(const __bf16* __restrict__ A,
                                                const __bf16* __restrict__ Bm,
                                                __bf16* __restrict__ Qp,
                                                __bf16* __restrict__ Kp,
                                                __bf16* __restrict__ Vp) {
  __shared__ __align__(16) __bf16 sA[4096];  // [128][32]
  __shared__ __align__(16) __bf16 sB[4096];
  const int tid = threadIdx.x;
  const int id = blockIdx.x;
  const int lg = (id & 7) * 72 + (id >> 3);  // bijective: 576 = 8*72
  const int m0 = (lg / 18) * 128, n0 = (lg % 18) * 128;
  const int lane = tid & 63, w = tid >> 6;
  const int wr = w >> 1, wc = w & 1;
  const int fr = lane & 15;
  const int ko = (lane >> 4) << 3;
  const int srow = lane >> 2, scol = (lane & 3) << 3;
  const __bf16* Ab = A + (size_t)(m0 + srow) * 768 + scol;
  const __bf16* Bb = Bm + (size_t)(n0 + srow) * 768 + scol;
  const int c0 = 2 * w, c1 = 2 * w + 1;
  f32x4 acc[4][4] = {};
  for (int k0 = 0; k0 < 768; k0 += 32) {
    GLOAD16(Ab + (size_t)c0 * 16 * 768 + k0, &sA[c0 * 512]);
    GLOAD16(Ab + (size_t)c1 * 16 * 768 + k0, &sA[c1 * 512]);
    GLOAD16(Bb + (size_t)c0 * 16 * 768 + k0, &sB[c0 * 512]);
    GLOAD16(Bb + (size_t)c1 * 16 * 768 + k0, &sB[c1 * 512]);
    __syncthreads();
    bf16x8 a[4], b[4];
#pragma unroll
    for (int m = 0; m < 4; ++m) a[m] = *(const bf16x8*)&sA[(wr * 64 + m * 16 + fr) * 32 + ko];
#pragma unroll
    for (int n = 0; n < 4; ++n) b[n] = *(const bf16x8*)&sB[(wc * 64 + n * 16 + fr) * 32 + ko];
#pragma unroll
    for (int m = 0; m < 4; ++m)
#pragma unroll
      for (int n = 0; n < 4; ++n)
        acc[m][n] = __builtin_amdgcn_mfma_f32_16x16x32_bf16(a[m], b[n], acc[m][n], 0, 0, 0);
    __syncthreads();
  }
  const int orow = (lane >> 4) << 2, ocol = lane & 15;
#pragma unroll
  for (int m = 0; m < 4; ++m)
#pragma unroll
    for (int n = 0; n < 4; ++n) {
      int r = m0 + wr * 64 + m * 16 + orow;  // token (4 consecutive via j)
      int c = n0 + wc * 64 + n * 16 + ocol;  // feature
      int sec = c / 768;
      int hd = c - sec * 768;
      int h = hd >> 6, d = hd & 63;
      int b = r >> 11, t = r & 2047;
      int bh = b * H_ + h;
      if (sec < 2) {
        int tile = t >> 5, rr = t & 31;
        int kc = d >> 4, half = (d >> 3) & 1, dj = d & 7;
        __bf16* dst = (sec == 0 ? Qp : Kp) + ((size_t)bh * 64 + tile) * 2048 +
                      kc * 512 + (half * 32 + rr) * 8 + dj;
#pragma unroll
        for (int j = 0; j < 4; ++j) dst[j * 8] = (__bf16)acc[m][n][j];  // rr+j
      } else {
        int chunk = t >> 6, sk = t & 63;
        int kc = sk >> 4, hf = (sk >> 3) & 1, j0 = sk & 7;  // j0 in {0,4}
        bf16x4 pk;
#pragma unroll
        for (int j = 0; j < 4; ++j) pk[j] = (__bf16)acc[m][n][j];
        *(bf16x4*)(Vp + ((size_t)bh * 32 + chunk) * 4096 + (d >> 5) * 2048 +
                   kc * 512 + (hf * 32 + (d & 31)) * 8 + j0) = pk;
      }
    }
}

// ---------------------------------------------------------------------------
// Stage-2 GEMM (bf16 in, fp32 out): out = y2b @ pb^T. Same m97 core.
// grid = 192 = 8 x 24, XCD-swizzled.
// ---------------------------------------------------------------------------
__global__ __launch_bounds__(256) void gemm_out(const __bf16* __restrict__ A,
                                                const __bf16* __restrict__ Bm,
                                                float* __restrict__ C) {
  __shared__ __align__(16) __bf16 sA[4096];
  __shared__ __align__(16) __bf16 sB[4096];
  const int tid = threadIdx.x;
  const int id = blockIdx.x;
  const int lg = (id & 7) * 24 + (id >> 3);  // bijective: 192 = 8*24
  const int m0 = (lg / 6) * 128, n0 = (lg % 6) * 128;
  const int lane = tid & 63, w = tid >> 6;
  const int wr = w >> 1, wc = w & 1;
  const int fr = lane & 15;
  const int ko = (lane >> 4) << 3;
  const int srow = lane >> 2, scol = (lane & 3) << 3;
  const __bf16* Ab = A + (size_t)(m0 + srow) * 768 + scol;
  const __bf16* Bb = Bm + (size_t)(n0 + srow) * 768 + scol;
  const int c0 = 2 * w, c1 = 2 * w + 1;
  f32x4 acc[4][4] = {};
  for (int k0 = 0; k0 < 768; k0 += 32) {
    GLOAD16(Ab + (size_t)c0 * 16 * 768 + k0, &sA[c0 * 512]);
    GLOAD16(Ab + (size_t)c1 * 16 * 768 + k0, &sA[c1 * 512]);
    GLOAD16(Bb + (size_t)c0 * 16 * 768 + k0, &sB[c0 * 512]);
    GLOAD16(Bb + (size_t)c1 * 16 * 768 + k0, &sB[c1 * 512]);
    __syncthreads();
    bf16x8 a[4], b[4];
#pragma unroll
    for (int m = 0; m < 4; ++m) a[m] = *(const bf16x8*)&sA[(wr * 64 + m * 16 + fr) * 32 + ko];
#pragma unroll
    for (int n = 0; n < 4; ++n) b[n] = *(const bf16x8*)&sB[(wc * 64 + n * 16 + fr) * 32 + ko];
#pragma unroll
    for (int m = 0; m < 4; ++m)
#pragma unroll
      for (int n = 0; n < 4; ++n)
        acc[m][n] = __builtin_amdgcn_mfma_f32_16x16x32_bf16(a[m], b[n], acc[m][n], 0, 0, 0);
    __syncthreads();
  }
  const int orow = (lane >> 4) << 2, ocol = lane & 15;
#pragma unroll
  for (int m = 0; m < 4; ++m)
#pragma unroll
    for (int n = 0; n < 4; ++n) {
      int r = m0 + wr * 64 + m * 16 + orow;
      int c = n0 + wc * 64 + n * 16 + ocol;
#pragma unroll
      for (int j = 0; j < 4; ++j) C[(size_t)(r + j) * 768 + c] = acc[m][n][j];
    }
}

// ---------------------------------------------------------------------------
// corr_mfma: loads + MFMA only; raw 32x32 tiles to Cw (bf16, coalesced).
// grid = 864 = 8 XCD x (3 bh x 36 (qb,tc) pairs).
// ---------------------------------------------------------------------------
__global__ __launch_bounds__(256) void corr_mfma(const __bf16* __restrict__ Qp,
                                                 const __bf16* __restrict__ Kp,
                                                 __bf16* __restrict__ Cw) {
  const int tid = threadIdx.x;
  int id = blockIdx.x;
  int sub = id >> 3;
  const int bh = (id & 7) * 3 + sub / 36;
  const int pi = sub % 36;
  int x = pi, qb = 0;
  while (x >= 8 - qb) { x -= 8 - qb; ++qb; }
  const int tc = qb + x;
  const int lane = tid & 63, w = tid >> 6;

  const __bf16* qp = Qp + ((size_t)bh << 17) + (lane << 3);
  const __bf16* kp = Kp + ((size_t)bh << 17) + (lane << 3);
  const int qA = 8 * qb + 2 * w;
  f32x16 acc0 = {}, acc1 = {};
  const bf16x8 zf = {};
  bf16x8 Af[2][4], Kc[2][4], Kpv[4];

  {  // prologue
    const int t0 = 8 * tc;
#pragma unroll
    for (int kc = 0; kc < 4; ++kc) Af[0][kc] = *(const bf16x8*)(qp + t0 * 2048 + kc * 512);
    const int s0 = t0 - qA, sm = s0 - 1;
#pragma unroll
    for (int kc = 0; kc < 4; ++kc) {
      Kc[0][kc] = (s0 >= 0) ? *(const bf16x8*)(kp + s0 * 2048 + kc * 512) : zf;
      Kpv[kc] = (sm >= 0) ? *(const bf16x8*)(kp + sm * 2048 + kc * 512) : zf;
    }
  }
#pragma unroll
  for (int ii = 0; ii < 8; ++ii) {
    const int cur = ii & 1, nxt = cur ^ 1;
    if (ii < 7) {
      const int tn = 8 * tc + ii + 1;
      const int sn = tn - qA;
#pragma unroll
      for (int kc = 0; kc < 4; ++kc) {
        Af[nxt][kc] = *(const bf16x8*)(qp + tn * 2048 + kc * 512);
        Kc[nxt][kc] = (sn >= 0) ? *(const bf16x8*)(kp + sn * 2048 + kc * 512) : zf;
      }
    }
#pragma unroll
    for (int kc = 0; kc < 4; ++kc) {
      acc0 = __builtin_amdgcn_mfma_f32_32x32x16_bf16(Af[cur][kc], Kc[cur][kc], acc0, 0, 0, 0);
      acc1 = __builtin_amdgcn_mfma_f32_32x32x16_bf16(Af[cur][kc], Kpv[kc], acc1, 0, 0, 0);
    }
#pragma unroll
    for (int kc = 0; kc < 4; ++kc) Kpv[kc] = Kc[cur][kc];
  }

  __bf16* o = Cw + (((size_t)(bh * 36 + pi) * 4 + w) * 2) * 1024 + lane;
#pragma unroll
  for (int j = 0; j < 16; ++j) {
    o[j * 64] = (__bf16)acc0[j];
    o[1024 + j * 64] = (__bf16)acc1[j];
  }
}

// ---------------------------------------------------------------------------
// corr_red: diagonal-reduce raw tiles. grid = 288 = 12 groups x 24 bh.
// ---------------------------------------------------------------------------
__global__ __launch_bounds__(256) void corr_red(const __bf16* __restrict__ Cw,
                                                float* __restrict__ P12) {
  __shared__ float tile[4][1056];   // [w][row*33+col]
  __shared__ float prow[4][2112];   // [w][lag+32]
  const int id = blockIdx.x;
  const int bh = id % 24, g = id / 24;
  const int tid = threadIdx.x, lane = tid & 63, w = tid >> 6;

  for (int i = tid; i < 4 * 2112; i += 256) ((float*)prow)[i] = 0.f;
  __syncthreads();

  const int col = lane & 31, hi = lane >> 5;
#pragma unroll
  for (int pp = 0; pp < 3; ++pp) {
    const int pi = g * 3 + pp;
    int x = pi, qb = 0;
    while (x >= 8 - qb) { x -= 8 - qb; ++qb; }
#pragma unroll
    for (int b01 = 0; b01 < 2; ++b01) {
      const __bf16* src =
          Cw + (((size_t)(bh * 36 + pi) * 4 + w) * 2 + b01) * 1024 + lane;
      float v[16];
#pragma unroll
      for (int j = 0; j < 16; ++j) v[j] = (float)src[j * 64];
#pragma unroll
      for (int j = 0; j < 16; ++j) {
        int row = (j & 3) + ((j >> 2) << 3) + 4 * hi;
        tile[w][row * 33 + col] = v[j];
      }
      __syncthreads();
      if (lane < 63) {
        const int d = lane - 31;
        float s = 0.f;
#pragma unroll
        for (int c = 0; c < 32; ++c) {
          int r = c + d;
          bool ok = (unsigned)r < 32u;
          float val = tile[w][(ok ? r : 0) * 33 + c];
          s += ok ? val : 0.f;
        }
        const int qA = 8 * qb + 2 * w + b01;
        prow[w][32 * qA + d + 32] += s;
      }
      __syncthreads();
    }
  }

  float* out = P12 + ((size_t)g * BH_ + bh) * T_;
  float ov[8];
#pragma unroll
  for (int u = 0; u < 8; ++u) {
    int L = (tid << 3) + u;
    ov[u] = prow[0][L + 32] + prow[1][L + 32] + prow[2][L + 32] + prow[3][L + 32];
  }
  *(f32x4*)(out + (tid << 3)) = *(f32x4*)&ov[0];
  *(f32x4*)(out + (tid << 3) + 4) = *(f32x4*)&ov[4];
}

// ---------------------------------------------------------------------------
// soft_k: reduce 12 partial slices -> Rb (phase-shifted reversed-e) + zinv.
// ---------------------------------------------------------------------------
__global__ __launch_bounds__(256) void soft_k(const float* __restrict__ P,
                                              const float* __restrict__ temp,
                                              __bf16* __restrict__ Rb,
                                              float* __restrict__ zinv) {
  __shared__ float se[T_];
  __shared__ float lm[4], wsum[4];
  const int bh = blockIdx.x, tid = threadIdx.x;
  const int lane = tid & 63, wid = tid >> 6;
  const float scale = 1.0f / (64.0f * (temp[0] + 1e-6f));
  f32x4 sa = {}, sb = {};
#pragma unroll
  for (int j = 0; j < 12; ++j) {
    const float* pp = P + ((size_t)j * BH_ + bh) * T_ + (tid << 3);
    sa += *(const f32x4*)pp;
    sb += *(const f32x4*)(pp + 4);
  }
  float v[8];
#pragma unroll
  for (int i = 0; i < 4; ++i) { v[i] = sa[i] * scale; v[4 + i] = sb[i] * scale; }
  float m = v[0];
#pragma unroll
  for (int i = 1; i < 8; ++i) m = fmaxf(m, v[i]);
#pragma unroll
  for (int off = 1; off < 64; off <<= 1) m = fmaxf(m, __shfl_xor(m, off));
  if (lane == 0) lm[wid] = m;
  __syncthreads();
  m = fmaxf(fmaxf(lm[0], lm[1]), fmaxf(lm[2], lm[3]));
  float ex[8], pr[8], run = 0;
#pragma unroll
  for (int i = 0; i < 8; ++i) { ex[i] = __expf(v[i] - m); run += ex[i]; pr[i] = run; }
  float s = run;
  for (int off = 1; off < 64; off <<= 1) {
    float o = __shfl_up(s, off);
    if (lane >= off) s += o;
  }
  if (lane == 63) wsum[wid] = s;
  __syncthreads();
  float base = s - run;
  for (int jw = 0; jw < wid; ++jw) base += wsum[jw];
#pragma unroll
  for (int i = 0; i < 8; ++i) {
    int t = (tid << 3) + i;
    zinv[(size_t)bh * T_ + t] = 1.0f / (base + pr[i]);
    se[t] = ex[i];
  }
  __syncthreads();
  __bf16* rb = Rb + (size_t)bh * 8 * RSTR;
  for (int c = tid; c < RSTR / 8; c += 256) {
    int i0 = c << 3;
#pragma unroll
    for (int p = 0; p < 8; ++p) {
      bf16x8 ovv;
#pragma unroll
      for (int e = 0; e < 8; ++e) {
        int idx = T_ - 1 - p - (i0 + e);
        ovv[e] = (__bf16)((idx >= 0) ? se[idx] : 0.f);
      }
      *(bf16x8*)(rb + p * RSTR + i0) = ovv;
    }
  }
}

// ---------------------------------------------------------------------------
// conv: Toeplitz MFMA, triple-buffered V-chunk pipeline; writes y2b (bf16).
// grid = 384 = 8 x (3 bh x 16 pairs), paired t-blocks {i,31-i}.
// ---------------------------------------------------------------------------
__global__ __launch_bounds__(256) void conv_k(const __bf16* __restrict__ Vp,
                                              const __bf16* __restrict__ Rb,
                                              const float* __restrict__ zinv,
                                              __bf16* __restrict__ y2b) {
  __shared__ __align__(16) __bf16 revc[8 * RSTR];
  const int tid = threadIdx.x;
  int id = blockIdx.x;
  int sub = id >> 3;
  const int bh = (id & 7) * 3 + (sub >> 4);
  const int pr = sub & 15;
  const int lane = tid & 63, w = tid >> 6;

  const __bf16* rb = Rb + (size_t)bh * 8 * RSTR;
  for (int c = tid; c < RSTR; c += 256)
    *(bf16x8*)&revc[c << 3] = *(const bf16x8*)(rb + ((size_t)c << 3));
  __syncthreads();

  const int fr = lane & 31, kg = (lane >> 5) << 3;
  const int tt = (w < 2) ? (64 * pr + 32 * w) : (64 * (31 - pr) + 32 * (w - 2));
  const int trow = tt + fr;
  const int pp = (T_ - 1 - trow) & 7;
  const int obase = (T_ - 1 - trow) - pp;
  const __bf16* vpb = Vp + (size_t)bh * 131072 + (lane << 3);
  f32x16 acc0 = {}, acc1 = {};
  const int nst = (tt >> 6) + 1;

  bf16x8 A00, A01, A02, A03, A10, A11, A12, A13;
  bf16x8 B00, B01, B02, B03, B10, B11, B12, B13;
  bf16x8 C00, C01, C02, C03, C10, C11, C12, C13;

#define LOADV(P, CH)                                                          \
  {                                                                           \
    const __bf16* vb_ = vpb + (size_t)(CH) * 4096;                            \
    P##00 = *(const bf16x8*)(vb_);          P##01 = *(const bf16x8*)(vb_ + 512);  \
    P##02 = *(const bf16x8*)(vb_ + 1024);   P##03 = *(const bf16x8*)(vb_ + 1536); \
    P##10 = *(const bf16x8*)(vb_ + 2048);   P##11 = *(const bf16x8*)(vb_ + 2560); \
    P##12 = *(const bf16x8*)(vb_ + 3072);   P##13 = *(const bf16x8*)(vb_ + 3584); \
  }
#define MSTEP(P, ST)                                                          \
  {                                                                           \
    const int ab_ = pp * RSTR + obase + (ST) * 64 + kg;                       \
    bf16x8 a0_ = *(const bf16x8*)&revc[ab_];                                  \
    bf16x8 a1_ = *(const bf16x8*)&revc[ab_ + 16];                             \
    bf16x8 a2_ = *(const bf16x8*)&revc[ab_ + 32];                             \
    bf16x8 a3_ = *(const bf16x8*)&revc[ab_ + 48];                             \
    acc0 = __builtin_amdgcn_mfma_f32_32x32x16_bf16(a0_, P##00, acc0, 0, 0, 0);\
    acc1 = __builtin_amdgcn_mfma_f32_32x32x16_bf16(a0_, P##10, acc1, 0, 0, 0);\
    acc0 = __builtin_amdgcn_mfma_f32_32x32x16_bf16(a1_, P##01, acc0, 0, 0, 0);\
    acc1 = __builtin_amdgcn_mfma_f32_32x32x16_bf16(a1_, P##11, acc1, 0, 0, 0);\
    acc0 = __builtin_amdgcn_mfma_f32_32x32x16_bf16(a2_, P##02, acc0, 0, 0, 0);\
    acc1 = __builtin_amdgcn_mfma_f32_32x32x16_bf16(a2_, P##12, acc1, 0, 0, 0);\
    acc0 = __builtin_amdgcn_mfma_f32_32x32x16_bf16(a3_, P##03, acc0, 0, 0, 0);\
    acc1 = __builtin_amdgcn_mfma_f32_32x32x16_bf16(a3_, P##13, acc1, 0, 0, 0);\
  }

  LOADV(A, 0);
  if (nst > 1) LOADV(B, 1);
  if (nst > 2) LOADV(C, 2);
  int st = 0;
  while (true) {
    MSTEP(A, st); if (st + 3 < nst) LOADV(A, st + 3); if (++st >= nst) break;
    MSTEP(B, st); if (st + 3 < nst) LOADV(B, st + 3); if (++st >= nst) break;
    MSTEP(C, st); if (st + 3 < nst) LOADV(C, st + 3); if (++st >= nst) break;
  }
#undef LOADV
#undef MSTEP

  const int b = bh / H_, h = bh % H_;
  const int ocol = lane & 31, rbj = (lane >> 5) << 2;
  const float* zp = zinv + (size_t)bh * T_;
#pragma unroll
  for (int j = 0; j < 16; ++j) {
    int row = (j & 3) + ((j >> 2) << 3) + rbj;
    int t = tt + row;
    float zi = zp[t];
    __bf16* yr = y2b + ((size_t)b * T_ + t) * C_ + h * 64;
    yr[ocol] = (__bf16)(acc0[j] * zi);
    yr[32 + ocol] = (__bf16)(acc1[j] * zi);
  }
}

// ---------------------------------------------------------------------------
extern "C" void kernel_launch(void* const* d_in, const int* in_sizes, int n_in,
                              void* d_out, int out_size, void* d_ws, size_t ws_size,
                              hipStream_t stream) {
  const float* x = (const float*)d_in[0];
  const float* c_attn = (const float*)d_in[1];
  const float* c_proj = (const float*)d_in[2];
  const float* temp = (const float*)d_in[3];
  float* out = (float*)d_out;

  // ws: Qp|Kp|Vp (18.9MB) | Rb | zinv | P12 | pb | zone (14.2MB).
  // zone holds xb+wb (die after gemm_qkv), then Cw (dies after corr_red),
  // then y2b (born at conv). ~37.6MB total.
  __bf16* Qp = (__bf16*)d_ws;
  __bf16* Kp = Qp + (size_t)3145728;
  __bf16* Vp = Kp + (size_t)3145728;
  __bf16* Rb = Vp + (size_t)3145728;                 // 422400 elems
  float* zinv = (float*)(Rb + 422400);               // 49152 floats
  float* P12 = zinv + 49152;                         // 589824 floats
  __bf16* pb = (__bf16*)(P12 + 589824);              // 589824 elems
  __bf16* zone = pb + 589824;                        // 7077888 elems
  __bf16* xb = zone;                                 // 3145728
  __bf16* wb = zone + 3145728;                       // 1769472
  __bf16* Cw = zone;                                 // 7077888 (= zone size)
  __bf16* y2b = zone;                                // 3145728

  cvt3_k<<<dim3(2688), 256, 0, stream>>>(x, c_attn, c_proj, xb, wb, pb);
  gemm_qkv<<<dim3(576), 256, 0, stream>>>(xb, wb, Qp, Kp, Vp);
  corr_mfma<<<dim3(864), 256, 0, stream>>>(Qp, Kp, Cw);
  corr_red<<<dim3(288), 256, 0, stream>>>(Cw, P12);
  soft_k<<<dim3(BH_), 256, 0, stream>>>(P12, temp, Rb, zinv);
  conv_k<<<dim3(384), 256, 0, stream>>>(Vp, Rb, zinv, y2b);
  gemm_out<<<dim3(192), 256, 0, stream>>>(y2b, pb, out);
}

// Round 9
// 94.845 us; speedup vs baseline: 1.6875x; 1.1690x over previous
//
#include <hip/hip_runtime.h>

#define T_ 2048
#define B_ 2
#define H_ 12
#define C_ 768
#define M_ 4096  // B*T
#define BH_ (B_ * H_)
#define RSTR 2200  // reversed-e padded stride

typedef __attribute__((ext_vector_type(4))) float f32x4;
typedef __attribute__((ext_vector_type(16))) float f32x16;
typedef __attribute__((ext_vector_type(8))) __bf16 bf16x8;
typedef __attribute__((ext_vector_type(4))) __bf16 bf16x4;

// async global->LDS, 16B per lane; LDS dest wave-uniform base + lane*16
#define GLOAD16(GP, LP)                                                   \
  __builtin_amdgcn_global_load_lds(                                       \
      (__attribute__((address_space(1))) void*)(GP),                      \
      (__attribute__((address_space(3))) void*)(LP), 16, 0, 0)

// Packed fragment-major layouts (coalesced MFMA frag loads):
//  Qp/Kp: [bh][tile=t>>5][kc=d>>4][lane=((d>>3)&1)*32 + (t&31)][j=d&7]
//  Vp:    [bh][chunk=t>>6][dhalf=d>>5][kc=(t&63)>>4][lane=(((t&63)>>3)&1)*32+(d&31)][j=t&7]

// ---------------------------------------------------------------------------
// cvt3: one-shot fp32 -> bf16 for x, c_attn, c_proj.
// ---------------------------------------------------------------------------
__global__ __launch_bounds__(256) void cvt3_k(const float* __restrict__ x,
                                              const float* __restrict__ ca,
                                              const float* __restrict__ cp,
                                              __bf16* __restrict__ xb,
                                              __bf16* __restrict__ wb,
                                              __bf16* __restrict__ pb) {
  const int id = blockIdx.x;
  const float* src;
  __bf16* dst;
  size_t base;
  if (id < 1536) { src = x; dst = xb; base = (size_t)id * 2048; }
  else if (id < 2400) { src = ca; dst = wb; base = (size_t)(id - 1536) * 2048; }
  else { src = cp; dst = pb; base = (size_t)(id - 2400) * 2048; }
  const size_t o = base + (size_t)threadIdx.x * 8;
  f32x4 v0 = *(const f32x4*)(src + o);
  f32x4 v1 = *(const f32x4*)(src + o + 4);
  bf16x8 r;
#pragma unroll
  for (int j = 0; j < 4; ++j) { r[j] = (__bf16)v0[j]; r[4 + j] = (__bf16)v1[j]; }
  *(bf16x8*)(dst + o) = r;
}

// ---------------------------------------------------------------------------
// Stage-1 GEMM (bf16): qkv = xb @ wb^T -> packed Qp, Kp, Vp.
// m97 recipe: 128x128, BK=32, global_load_lds(16B), linear LDS, 2 barriers.
// ---------------------------------------------------------------------------
__global__ __launch_bounds__(256) void gemm_qkv(const __bf16* __restrict__ A,
                                                const __bf16* __restrict__ Bm,
                                                __bf16* __restrict__ Qp,
                                                __bf16* __restrict__ Kp,
                                                __bf16* __restrict__ Vp) {
  __shared__ __align__(16) __bf16 sA[4096];  // [128][32]
  __shared__ __align__(16) __bf16 sB[4096];
  const int tid = threadIdx.x;
  const int id = blockIdx.x;
  const int lg = (id & 7) * 72 + (id >> 3);  // bijective: 576 = 8*72
  const int m0 = (lg / 18) * 128, n0 = (lg % 18) * 128;
  const int lane = tid & 63, w = tid >> 6;
  const int wr = w >> 1, wc = w & 1;
  const int fr = lane & 15;
  const int ko = (lane >> 4) << 3;
  const int srow = lane >> 2, scol = (lane & 3) << 3;
  const __bf16* Ab = A + (size_t)(m0 + srow) * 768 + scol;
  const __bf16* Bb = Bm + (size_t)(n0 + srow) * 768 + scol;
  const int c0 = 2 * w, c1 = 2 * w + 1;
  f32x4 acc[4][4] = {};
  for (int k0 = 0; k0 < 768; k0 += 32) {
    GLOAD16(Ab + (size_t)c0 * 16 * 768 + k0, &sA[c0 * 512]);
    GLOAD16(Ab + (size_t)c1 * 16 * 768 + k0, &sA[c1 * 512]);
    GLOAD16(Bb + (size_t)c0 * 16 * 768 + k0, &sB[c0 * 512]);
    GLOAD16(Bb + (size_t)c1 * 16 * 768 + k0, &sB[c1 * 512]);
    __syncthreads();
    bf16x8 a[4], b[4];
#pragma unroll
    for (int m = 0; m < 4; ++m) a[m] = *(const bf16x8*)&sA[(wr * 64 + m * 16 + fr) * 32 + ko];
#pragma unroll
    for (int n = 0; n < 4; ++n) b[n] = *(const bf16x8*)&sB[(wc * 64 + n * 16 + fr) * 32 + ko];
#pragma unroll
    for (int m = 0; m < 4; ++m)
#pragma unroll
      for (int n = 0; n < 4; ++n)
        acc[m][n] = __builtin_amdgcn_mfma_f32_16x16x32_bf16(a[m], b[n], acc[m][n], 0, 0, 0);
    __syncthreads();
  }
  const int orow = (lane >> 4) << 2, ocol = lane & 15;
#pragma unroll
  for (int m = 0; m < 4; ++m)
#pragma unroll
    for (int n = 0; n < 4; ++n) {
      int r = m0 + wr * 64 + m * 16 + orow;  // token (4 consecutive via j)
      int c = n0 + wc * 64 + n * 16 + ocol;  // feature
      int sec = c / 768;
      int hd = c - sec * 768;
      int h = hd >> 6, d = hd & 63;
      int b = r >> 11, t = r & 2047;
      int bh = b * H_ + h;
      if (sec < 2) {
        int tile = t >> 5, rr = t & 31;
        int kc = d >> 4, half = (d >> 3) & 1, dj = d & 7;
        __bf16* dst = (sec == 0 ? Qp : Kp) + ((size_t)bh * 64 + tile) * 2048 +
                      kc * 512 + (half * 32 + rr) * 8 + dj;
#pragma unroll
        for (int j = 0; j < 4; ++j) dst[j * 8] = (__bf16)acc[m][n][j];  // rr+j
      } else {
        int chunk = t >> 6, sk = t & 63;
        int kc = sk >> 4, hf = (sk >> 3) & 1, j0 = sk & 7;  // j0 in {0,4}
        bf16x4 pk;
#pragma unroll
        for (int j = 0; j < 4; ++j) pk[j] = (__bf16)acc[m][n][j];
        *(bf16x4*)(Vp + ((size_t)bh * 32 + chunk) * 4096 + (d >> 5) * 2048 +
                   kc * 512 + (hf * 32 + (d & 31)) * 8 + j0) = pk;
      }
    }
}

// ---------------------------------------------------------------------------
// Stage-2 GEMM (bf16 in, fp32 out): out = y2b @ pb^T.
// 64x64 tiles for latency hiding: grid = 768 = 8 x 96 (XCD-swizzled),
// 4 waves 2x2, each wave 32x32 out, 2 GLOAD16 + 4 MFMA per K-step.
// ---------------------------------------------------------------------------
__global__ __launch_bounds__(256) void gemm_out(const __bf16* __restrict__ A,
                                                const __bf16* __restrict__ Bm,
                                                float* __restrict__ C) {
  __shared__ __align__(16) __bf16 sA[2048];  // [64][32]
  __shared__ __align__(16) __bf16 sB[2048];
  const int tid = threadIdx.x;
  const int id = blockIdx.x;
  const int lg = (id & 7) * 96 + (id >> 3);  // bijective: 768 = 8*96
  const int m0 = (lg / 12) * 64, n0 = (lg % 12) * 64;
  const int lane = tid & 63, w = tid >> 6;
  const int wr = w >> 1, wc = w & 1;
  const int fr = lane & 15;
  const int ko = (lane >> 4) << 3;
  const int srow = tid >> 2, scol = (tid & 3) << 3;
  const __bf16* Ab = A + (size_t)(m0 + srow) * 768 + scol;
  const __bf16* Bb = Bm + (size_t)(n0 + srow) * 768 + scol;
  f32x4 acc[2][2] = {};
  for (int k0 = 0; k0 < 768; k0 += 32) {
    GLOAD16(Ab + k0, &sA[w * 512]);
    GLOAD16(Bb + k0, &sB[w * 512]);
    __syncthreads();
    bf16x8 a[2], b[2];
#pragma unroll
    for (int m = 0; m < 2; ++m) a[m] = *(const bf16x8*)&sA[(wr * 32 + m * 16 + fr) * 32 + ko];
#pragma unroll
    for (int n = 0; n < 2; ++n) b[n] = *(const bf16x8*)&sB[(wc * 32 + n * 16 + fr) * 32 + ko];
#pragma unroll
    for (int m = 0; m < 2; ++m)
#pragma unroll
      for (int n = 0; n < 2; ++n)
        acc[m][n] = __builtin_amdgcn_mfma_f32_16x16x32_bf16(a[m], b[n], acc[m][n], 0, 0, 0);
    __syncthreads();
  }
  const int orow = (lane >> 4) << 2, ocol = lane & 15;
#pragma unroll
  for (int m = 0; m < 2; ++m)
#pragma unroll
    for (int n = 0; n < 2; ++n) {
      int r = m0 + wr * 32 + m * 16 + orow;
      int c = n0 + wc * 32 + n * 16 + ocol;
#pragma unroll
      for (int j = 0; j < 4; ++j) C[(size_t)(r + j) * 768 + c] = acc[m][n][j];
    }
}

// ---------------------------------------------------------------------------
// corr_k2: fused diagonal-band MFMA + ATOMIC-FREE diag reduction.
// Core = R7's corr_mfma (proven). Epilogue = R7's corr_red scheme (proven):
// per-wave LDS tile[32][33] stage -> 63-lane predicated diag sums ->
// per-wave 288-entry prow window -> merge -> full P36 row.
// grid = 864 = 8 XCD x (3 bh x 36 (qb,tc) pairs).
// ---------------------------------------------------------------------------
__global__ __launch_bounds__(256) void corr_k2(const __bf16* __restrict__ Qp,
                                               const __bf16* __restrict__ Kp,
                                               float* __restrict__ P36) {
  __shared__ float tile[4][1056];  // [w][row*33+col]
  __shared__ float prow[4][288];   // [w][local lag + 32], window 256qb-31..+255
  const int tid = threadIdx.x;
  int id = blockIdx.x;
  int sub = id >> 3;
  const int bh = (id & 7) * 3 + sub / 36;
  const int pi = sub % 36;
  int x = pi, qb = 0;
  while (x >= 8 - qb) { x -= 8 - qb; ++qb; }
  const int tc = qb + x;
  const int lane = tid & 63, w = tid >> 6;

  for (int i = tid; i < 4 * 288; i += 256) ((float*)prow)[i] = 0.f;

  const __bf16* qp = Qp + ((size_t)bh << 17) + (lane << 3);
  const __bf16* kp = Kp + ((size_t)bh << 17) + (lane << 3);
  const int qA = 8 * qb + 2 * w;
  f32x16 acc0 = {}, acc1 = {};
  const bf16x8 zf = {};
  bf16x8 Af[2][4], Kc[2][4], Kpv[4];

  {  // prologue
    const int t0 = 8 * tc;
#pragma unroll
    for (int kc = 0; kc < 4; ++kc) Af[0][kc] = *(const bf16x8*)(qp + t0 * 2048 + kc * 512);
    const int s0 = t0 - qA, sm = s0 - 1;
#pragma unroll
    for (int kc = 0; kc < 4; ++kc) {
      Kc[0][kc] = (s0 >= 0) ? *(const bf16x8*)(kp + s0 * 2048 + kc * 512) : zf;
      Kpv[kc] = (sm >= 0) ? *(const bf16x8*)(kp + sm * 2048 + kc * 512) : zf;
    }
  }
#pragma unroll
  for (int ii = 0; ii < 8; ++ii) {
    const int cur = ii & 1, nxt = cur ^ 1;
    if (ii < 7) {
      const int tn = 8 * tc + ii + 1;
      const int sn = tn - qA;
#pragma unroll
      for (int kc = 0; kc < 4; ++kc) {
        Af[nxt][kc] = *(const bf16x8*)(qp + tn * 2048 + kc * 512);
        Kc[nxt][kc] = (sn >= 0) ? *(const bf16x8*)(kp + sn * 2048 + kc * 512) : zf;
      }
    }
#pragma unroll
    for (int kc = 0; kc < 4; ++kc) {
      acc0 = __builtin_amdgcn_mfma_f32_32x32x16_bf16(Af[cur][kc], Kc[cur][kc], acc0, 0, 0, 0);
      acc1 = __builtin_amdgcn_mfma_f32_32x32x16_bf16(Af[cur][kc], Kpv[kc], acc1, 0, 0, 0);
    }
#pragma unroll
    for (int kc = 0; kc < 4; ++kc) Kpv[kc] = Kc[cur][kc];
  }

  // ---- fused atomic-free diagonal reduction ----
  const int col = lane & 31, hi = lane >> 5;
  const int d = lane - 31;  // diag owned by lanes 0..62
  __syncthreads();          // prow zero complete (+ MFMA loop done everywhere)
#pragma unroll
  for (int b01 = 0; b01 < 2; ++b01) {
    const f32x16* ac = (b01 == 0) ? &acc0 : &acc1;
#pragma unroll
    for (int j = 0; j < 16; ++j) {
      int row = (j & 3) + ((j >> 2) << 3) + 4 * hi;
      tile[w][row * 33 + col] = (*ac)[j];
    }
    __syncthreads();
    if (lane < 63) {
      float s = 0.f;
#pragma unroll
      for (int c = 0; c < 32; ++c) {
        int r = c + d;
        bool ok = (unsigned)r < 32u;
        float val = tile[w][(ok ? r : 0) * 33 + c];
        s += ok ? val : 0.f;
      }
      // local band index qL = 2w+b01; local lag = 32*qL + d
      prow[w][32 * (2 * w + b01) + d + 32] += s;
    }
    __syncthreads();
  }

  // merge 4 per-wave windows; write full row of unique slice pi
  float* Pd = P36 + ((size_t)pi * BH_ + bh) * T_;
  float ov[8];
#pragma unroll
  for (int u = 0; u < 8; ++u) {
    int L = (tid << 3) + u;
    int l = L - 256 * qb;
    float s = 0.f;
    if (l >= -31 && l < 256)
      s = prow[0][l + 32] + prow[1][l + 32] + prow[2][l + 32] + prow[3][l + 32];
    ov[u] = s;
  }
  *(f32x4*)(Pd + (tid << 3)) = *(f32x4*)&ov[0];
  *(f32x4*)(Pd + (tid << 3) + 4) = *(f32x4*)&ov[4];
}

// ---------------------------------------------------------------------------
// soft_k: reduce 36 partial slices -> Rb (phase-shifted reversed-e) + zinv.
// ---------------------------------------------------------------------------
__global__ __launch_bounds__(256) void soft_k(const float* __restrict__ P,
                                              const float* __restrict__ temp,
                                              __bf16* __restrict__ Rb,
                                              float* __restrict__ zinv) {
  __shared__ float se[T_];
  __shared__ float lm[4], wsum[4];
  const int bh = blockIdx.x, tid = threadIdx.x;
  const int lane = tid & 63, wid = tid >> 6;
  const float scale = 1.0f / (64.0f * (temp[0] + 1e-6f));
  f32x4 sa = {}, sb = {};
#pragma unroll
  for (int j = 0; j < 36; ++j) {
    const float* pp = P + ((size_t)j * BH_ + bh) * T_ + (tid << 3);
    sa += *(const f32x4*)pp;
    sb += *(const f32x4*)(pp + 4);
  }
  float v[8];
#pragma unroll
  for (int i = 0; i < 4; ++i) { v[i] = sa[i] * scale; v[4 + i] = sb[i] * scale; }
  float m = v[0];
#pragma unroll
  for (int i = 1; i < 8; ++i) m = fmaxf(m, v[i]);
#pragma unroll
  for (int off = 1; off < 64; off <<= 1) m = fmaxf(m, __shfl_xor(m, off));
  if (lane == 0) lm[wid] = m;
  __syncthreads();
  m = fmaxf(fmaxf(lm[0], lm[1]), fmaxf(lm[2], lm[3]));
  float ex[8], pr[8], run = 0;
#pragma unroll
  for (int i = 0; i < 8; ++i) { ex[i] = __expf(v[i] - m); run += ex[i]; pr[i] = run; }
  float s = run;
  for (int off = 1; off < 64; off <<= 1) {
    float o = __shfl_up(s, off);
    if (lane >= off) s += o;
  }
  if (lane == 63) wsum[wid] = s;
  __syncthreads();
  float base = s - run;
  for (int jw = 0; jw < wid; ++jw) base += wsum[jw];
#pragma unroll
  for (int i = 0; i < 8; ++i) {
    int t = (tid << 3) + i;
    zinv[(size_t)bh * T_ + t] = 1.0f / (base + pr[i]);
    se[t] = ex[i];
  }
  __syncthreads();
  __bf16* rb = Rb + (size_t)bh * 8 * RSTR;
  for (int c = tid; c < RSTR / 8; c += 256) {
    int i0 = c << 3;
#pragma unroll
    for (int p = 0; p < 8; ++p) {
      bf16x8 ovv;
#pragma unroll
      for (int e = 0; e < 8; ++e) {
        int idx = T_ - 1 - p - (i0 + e);
        ovv[e] = (__bf16)((idx >= 0) ? se[idx] : 0.f);
      }
      *(bf16x8*)(rb + p * RSTR + i0) = ovv;
    }
  }
}

// ---------------------------------------------------------------------------
// conv: Toeplitz MFMA, triple-buffered V-chunk pipeline; writes y2b (bf16).
// grid = 384 = 8 x (3 bh x 16 pairs), paired t-blocks {i,31-i}.
// ---------------------------------------------------------------------------
__global__ __launch_bounds__(256) void conv_k(const __bf16* __restrict__ Vp,
                                              const __bf16* __restrict__ Rb,
                                              const float* __restrict__ zinv,
                                              __bf16* __restrict__ y2b) {
  __shared__ __align__(16) __bf16 revc[8 * RSTR];
  const int tid = threadIdx.x;
  int id = blockIdx.x;
  int sub = id >> 3;
  const int bh = (id & 7) * 3 + (sub >> 4);
  const int pr = sub & 15;
  const int lane = tid & 63, w = tid >> 6;

  const __bf16* rb = Rb + (size_t)bh * 8 * RSTR;
  for (int c = tid; c < RSTR; c += 256)
    *(bf16x8*)&revc[c << 3] = *(const bf16x8*)(rb + ((size_t)c << 3));
  __syncthreads();

  const int fr = lane & 31, kg = (lane >> 5) << 3;
  const int tt = (w < 2) ? (64 * pr + 32 * w) : (64 * (31 - pr) + 32 * (w - 2));
  const int trow = tt + fr;
  const int pp = (T_ - 1 - trow) & 7;
  const int obase = (T_ - 1 - trow) - pp;
  const __bf16* vpb = Vp + (size_t)bh * 131072 + (lane << 3);
  f32x16 acc0 = {}, acc1 = {};
  const int nst = (tt >> 6) + 1;

  bf16x8 A00, A01, A02, A03, A10, A11, A12, A13;
  bf16x8 B00, B01, B02, B03, B10, B11, B12, B13;
  bf16x8 C00, C01, C02, C03, C10, C11, C12, C13;

#define LOADV(P, CH)                                                          \
  {                                                                           \
    const __bf16* vb_ = vpb + (size_t)(CH) * 4096;                            \
    P##00 = *(const bf16x8*)(vb_);          P##01 = *(const bf16x8*)(vb_ + 512);  \
    P##02 = *(const bf16x8*)(vb_ + 1024);   P##03 = *(const bf16x8*)(vb_ + 1536); \
    P##10 = *(const bf16x8*)(vb_ + 2048);   P##11 = *(const bf16x8*)(vb_ + 2560); \
    P##12 = *(const bf16x8*)(vb_ + 3072);   P##13 = *(const bf16x8*)(vb_ + 3584); \
  }
#define MSTEP(P, ST)                                                          \
  {                                                                           \
    const int ab_ = pp * RSTR + obase + (ST) * 64 + kg;                       \
    bf16x8 a0_ = *(const bf16x8*)&revc[ab_];                                  \
    bf16x8 a1_ = *(const bf16x8*)&revc[ab_ + 16];                             \
    bf16x8 a2_ = *(const bf16x8*)&revc[ab_ + 32];                             \
    bf16x8 a3_ = *(const bf16x8*)&revc[ab_ + 48];                             \
    acc0 = __builtin_amdgcn_mfma_f32_32x32x16_bf16(a0_, P##00, acc0, 0, 0, 0);\
    acc1 = __builtin_amdgcn_mfma_f32_32x32x16_bf16(a0_, P##10, acc1, 0, 0, 0);\
    acc0 = __builtin_amdgcn_mfma_f32_32x32x16_bf16(a1_, P##01, acc0, 0, 0, 0);\
    acc1 = __builtin_amdgcn_mfma_f32_32x32x16_bf16(a1_, P##11, acc1, 0, 0, 0);\
    acc0 = __builtin_amdgcn_mfma_f32_32x32x16_bf16(a2_, P##02, acc0, 0, 0, 0);\
    acc1 = __builtin_amdgcn_mfma_f32_32x32x16_bf16(a2_, P##12, acc1, 0, 0, 0);\
    acc0 = __builtin_amdgcn_mfma_f32_32x32x16_bf16(a3_, P##03, acc0, 0, 0, 0);\
    acc1 = __builtin_amdgcn_mfma_f32_32x32x16_bf16(a3_, P##13, acc1, 0, 0, 0);\
  }

  LOADV(A, 0);
  if (nst > 1) LOADV(B, 1);
  if (nst > 2) LOADV(C, 2);
  int st = 0;
  while (true) {
    MSTEP(A, st); if (st + 3 < nst) LOADV(A, st + 3); if (++st >= nst) break;
    MSTEP(B, st); if (st + 3 < nst) LOADV(B, st + 3); if (++st >= nst) break;
    MSTEP(C, st); if (st + 3 < nst) LOADV(C, st + 3); if (++st >= nst) break;
  }
#undef LOADV
#undef MSTEP

  const int b = bh / H_, h = bh % H_;
  const int ocol = lane & 31, rbj = (lane >> 5) << 2;
  const float* zp = zinv + (size_t)bh * T_;
#pragma unroll
  for (int j = 0; j < 16; ++j) {
    int row = (j & 3) + ((j >> 2) << 3) + rbj;
    int t = tt + row;
    float zi = zp[t];
    __bf16* yr = y2b + ((size_t)b * T_ + t) * C_ + h * 64;
    yr[ocol] = (__bf16)(acc0[j] * zi);
    yr[32 + ocol] = (__bf16)(acc1[j] * zi);
  }
}

// ---------------------------------------------------------------------------
extern "C" void kernel_launch(void* const* d_in, const int* in_sizes, int n_in,
                              void* d_out, int out_size, void* d_ws, size_t ws_size,
                              hipStream_t stream) {
  const float* x = (const float*)d_in[0];
  const float* c_attn = (const float*)d_in[1];
  const float* c_proj = (const float*)d_in[2];
  const float* temp = (const float*)d_in[3];
  float* out = (float*)d_out;

  // ws (elems): Qp|Kp|Vp bf16 | Rb bf16 | zinv f32 | P36 f32 | pb bf16 |
  // xb bf16 (aliased by y2b after gemm_qkv) | wb bf16.  ~38.0 MB.
  __bf16* Qp = (__bf16*)d_ws;
  __bf16* Kp = Qp + (size_t)3145728;
  __bf16* Vp = Kp + (size_t)3145728;
  __bf16* Rb = Vp + (size_t)3145728;            // 422400
  float* zinv = (float*)(Rb + 422400);          // 49152
  float* P36 = zinv + 49152;                    // 1769472
  __bf16* pb = (__bf16*)(P36 + 1769472);        // 589824
  __bf16* xb = pb + 589824;                     // 3145728
  __bf16* wb = xb + 3145728;                    // 1769472
  __bf16* y2b = xb;                             // alias: xb dead after gemm_qkv

  cvt3_k<<<dim3(2688), 256, 0, stream>>>(x, c_attn, c_proj, xb, wb, pb);
  gemm_qkv<<<dim3(576), 256, 0, stream>>>(xb, wb, Qp, Kp, Vp);
  corr_k2<<<dim3(864), 256, 0, stream>>>(Qp, Kp, P36);
  soft_k<<<dim3(BH_), 256, 0, stream>>>(P36, temp, Rb, zinv);
  conv_k<<<dim3(384), 256, 0, stream>>>(Vp, Rb, zinv, y2b);
  gemm_out<<<dim3(768), 256, 0, stream>>>(y2b, pb, out);
}